// Round 25
// baseline (63.549 us; speedup 1.0000x reference)
//
#include <hip/hip_runtime.h>

// Resample 48k -> 10k via MFMA, 3-phase-set packing, SINGLE KERNEL.
// y[5k+d] = sum_{cc} Tap[cc][d]*x[24k-48+cc]. Column j=5D+d (D=0..2), row r
// covers k=k0+3r+D: Y[r][5D+d]=sum_c A[r][c]*B[c][5D+d], K=192 -> 6 MFMA.
// Wave-tile = 48 k / 240 outputs. A layout: row=lane&15, k=32m+8(lane>>4)+j.
// C/D [m89]: col=lane&15, row=4*(lane>>4)+reg -> k = kgen+48wv+12q+3*reg+D.
//
// R25 delta vs R22 (41.8us best): B fragments computed IN-KERNEL per block
// (48 guarded h-gathers, h=1.9kB L1-resident, + 24 cvt_pk; amortized over 4
// gens) -> prep kernel + its graph-serial launch/drain (~2-4us) removed.
// Store path = R22's direct scattered stores (R23 transpose was -0.8us).

#define NIN    1440000
#define NOUTR  300000
#define NROWS  32
#define KTOT   60000
#define KB     192               // k per gen (4 waves x 48)
#define GENS   313               // ceil(60000/192)
#define S      4                 // gens per block
#define NBX    79                // ceil(313/4)
#define TILE_E 4752              // 24*(KB-1) + 168 window floats
#define NU8    594               // 8-float staging units (4752/8)

typedef __attribute__((ext_vector_type(8))) short short8v;
typedef __attribute__((ext_vector_type(4))) float float4v;

__global__ __launch_bounds__(256, 5) void resample_kernel(
    const float* __restrict__ x, const float* __restrict__ h,
    float* __restrict__ y)
{
    __shared__ __align__(16) short ldsb[TILE_E];   // bf16 tile, 9504 B
    const int tid  = threadIdx.x;
    const int lane = tid & 63;
    const int wv   = tid >> 6;                     // 0..3: 48-k group per wave
    const int row  = blockIdx.y;
    const int gb   = blockIdx.x * S;               // first gen
    const int n    = min(S, GENS - gb);            // block-uniform, >=1
    const float* __restrict__ xr = x + (size_t)row * NIN;

    const int q = lane >> 4, r = lane & 15;
    const int col = r;                             // C/D col = lane&15
    const int D = col / 5, d = col - 5 * D;        // phase-set, phase

    // ---- B fragments computed in-registers (once per block) ----
    // B[c][col] = Tap[c-24D][d] = 5*h[24d+480-5(c-24D)], c = 32m+8q+j.
    short8v Bf[6];
    #pragma unroll
    for (int m = 0; m < 6; ++m) {
        unsigned w[4];
        #pragma unroll
        for (int jp = 0; jp < 4; ++jp) {           // tap pair j=2jp, 2jp+1
            float v0 = 0.f, v1 = 0.f;
            if (col < 15) {
                const int c0 = 32 * m + 8 * q + 2 * jp;
                const int t0 = 24 * d + 480 - 5 * (c0 - 24 * D);
                const int t1 = t0 - 5;
                v0 = (t0 >= 0 && t0 <= 480) ? h[t0] * 5.0f : 0.0f;
                v1 = (t1 >= 0 && t1 <= 480) ? h[t1] * 5.0f : 0.0f;
            }
            asm("v_cvt_pk_bf16_f32 %0, %1, %2" : "=v"(w[jp]) : "v"(v0), "v"(v1));
        }
        Bf[m] = __builtin_bit_cast(short8v, make_uint4(w[0], w[1], w[2], w[3]));
    }

    const int aoff = 1152 * wv + 72 * r + 8 * q;   // lane's A base (elems)

    for (int s = 0; s < n; ++s) {
        const int kgen = KB * (gb + s);            // gen's base k
        const int gg = 24 * kgen - 48;             // tile start; 16B-aligned
        __syncthreads();                           // prior gen's reads done

        // ---- stage tile: 8 floats/unit -> 4x cvt_pk -> one ds_write_b128 ----
        if (gg >= 0 && gg + TILE_E <= NIN) {       // interior fast path
            const float4* __restrict__ p = reinterpret_cast<const float4*>(xr + gg);
            auto stu = [&](int u) {
                const float4 pa = p[2 * u], pb = p[2 * u + 1];
                unsigned r0, r1, r2, r3;
                asm("v_cvt_pk_bf16_f32 %0, %1, %2" : "=v"(r0) : "v"(pa.x), "v"(pa.y));
                asm("v_cvt_pk_bf16_f32 %0, %1, %2" : "=v"(r1) : "v"(pa.z), "v"(pa.w));
                asm("v_cvt_pk_bf16_f32 %0, %1, %2" : "=v"(r2) : "v"(pb.x), "v"(pb.y));
                asm("v_cvt_pk_bf16_f32 %0, %1, %2" : "=v"(r3) : "v"(pb.z), "v"(pb.w));
                *reinterpret_cast<uint4*>(&ldsb[8 * u]) = make_uint4(r0, r1, r2, r3);
            };
            stu(tid);
            stu(tid + 256);
            if (tid < NU8 - 512) stu(tid + 512);
        } else {                                   // first/last gens only
            auto stu = [&](int u) {
                float v[8];
                #pragma unroll
                for (int j = 0; j < 8; ++j) {
                    const int g = gg + 8 * u + j;
                    v[j] = ((unsigned)g < NIN) ? xr[g] : 0.0f;
                }
                unsigned r0, r1, r2, r3;
                asm("v_cvt_pk_bf16_f32 %0, %1, %2" : "=v"(r0) : "v"(v[0]), "v"(v[1]));
                asm("v_cvt_pk_bf16_f32 %0, %1, %2" : "=v"(r1) : "v"(v[2]), "v"(v[3]));
                asm("v_cvt_pk_bf16_f32 %0, %1, %2" : "=v"(r2) : "v"(v[4]), "v"(v[5]));
                asm("v_cvt_pk_bf16_f32 %0, %1, %2" : "=v"(r3) : "v"(v[6]), "v"(v[7]));
                *reinterpret_cast<uint4*>(&ldsb[8 * u]) = make_uint4(r0, r1, r2, r3);
            };
            stu(tid);
            stu(tid + 256);
            if (tid < NU8 - 512) stu(tid + 512);
        }
        __syncthreads();                           // tile staged

        // ---- compute: A fragments + MFMA chain over K=192 ----
        const short* __restrict__ ap = &ldsb[aoff];
        float4v acc = {0.f, 0.f, 0.f, 0.f};
        #pragma unroll
        for (int m = 0; m < 6; ++m) {
            const short8v A = *reinterpret_cast<const short8v*>(ap + 32 * m);
            acc = __builtin_amdgcn_mfma_f32_16x16x32_bf16(A, Bf[m], acc, 0, 0, 0);
        }

        // ---- stores: k = kgen + 48wv + 12q + 3*reg + D, phase d ----
        if (col < 15) {
            const int kw = kgen + 48 * wv + 12 * q + D;
            float* __restrict__ yr = y + (size_t)row * NOUTR;
            #pragma unroll
            for (int jj = 0; jj < 4; ++jj) {
                const int k = kw + 3 * jj;
                if (k < KTOT) yr[5 * (size_t)k + d] = acc[jj];
            }
        }
    }
}

extern "C" void kernel_launch(void* const* d_in, const int* in_sizes, int n_in,
                              void* d_out, int out_size, void* d_ws, size_t ws_size,
                              hipStream_t stream) {
    const float* x = (const float*)d_in[0];
    const float* h = (const float*)d_in[1];        // 481 taps
    float* y = (float*)d_out;                      // 32 x 300000 f32

    dim3 grid(NBX, NROWS);                         // 79 x 32, 256-thr blocks
    resample_kernel<<<grid, 256, 0, stream>>>(x, h, y);
}

// Round 26
// 41.478 us; speedup vs baseline: 1.5321x; 1.5321x over previous
//
#include <hip/hip_runtime.h>

// Resample 48k -> 10k via MFMA, 3-phase-set packing (R22 — session best 41.8us).
// y[5k+d] = sum_{cc} Tap[cc][d]*x[24k-48+cc]. Column j=5D+d (D=0..2), row r
// covers k=k0+3r+D: Y[r][5D+d]=sum_c A[r][c]*B[c][5D+d], K=192 -> 6 MFMA.
// Wave-tile = 48 k / 240 outputs. A layout: row=lane&15, k=32m+8(lane>>4)+j.
// C/D [m89]: col=lane&15, row=4*(lane>>4)+reg -> k = kgen+48wv+12q+3*reg+D.
//
// R26 = exact R22 revert. R25 lesson: B must come from the prep-packed ws
// table — in-kernel h-gathers can't be register-cached across the gen loop
// (y-store aliasing forces re-loads; VGPR_Count collapsed 90->28, 42->64us).

#define NIN    1440000
#define NOUTR  300000
#define NROWS  32
#define KTOT   60000
#define KB     192               // k per gen (4 waves x 48)
#define GENS   313               // ceil(60000/192)
#define S      4                 // gens per block
#define NBX    79                // ceil(313/4)
#define TILE_E 4752              // 24*(KB-1) + 168 window floats
#define NU8    594               // 8-float staging units (4752/8)

typedef __attribute__((ext_vector_type(8))) short short8v;
typedef __attribute__((ext_vector_type(4))) float float4v;

__device__ __forceinline__ unsigned short f2b(float f) {
    unsigned u = __builtin_bit_cast(unsigned, f);
    u += 0x7fff + ((u >> 16) & 1);                 // RNE
    return (unsigned short)(u >> 16);
}

// Bpk[(m*64+l)*8+j] = bf16( B[c=32m+8*(l>>4)+j][col=l&15] ), 6KB in ws.
__global__ void prep_taps_kernel(const float* __restrict__ h,
                                 unsigned short* __restrict__ Bpk) {
    int i = blockIdx.x * blockDim.x + threadIdx.x;     // 0..3071
    if (i < 3072) {
        int j = i & 7, l = (i >> 3) & 63, m = i >> 9;  // m 0..5
        int col = l & 15, q = l >> 4;
        int c = 32 * m + 8 * q + j;
        int D = col / 5, d = col - 5 * D;
        int t = 24 * d + 480 - 5 * (c - 24 * D);
        float v = (col < 15 && t >= 0 && t <= 480) ? h[t] * 5.0f : 0.0f;
        Bpk[i] = f2b(v);
    }
}

__global__ __launch_bounds__(256, 5) void resample_kernel(
    const float* __restrict__ x, const unsigned short* __restrict__ Bpk,
    float* __restrict__ y)
{
    __shared__ __align__(16) short ldsb[TILE_E];   // bf16 tile, 9504 B
    const int tid  = threadIdx.x;
    const int lane = tid & 63;
    const int wv   = tid >> 6;                     // 0..3: 48-k group per wave
    const int row  = blockIdx.y;
    const int gb   = blockIdx.x * S;               // first gen
    const int n    = min(S, GENS - gb);            // block-uniform, >=1
    const float* __restrict__ xr = x + (size_t)row * NIN;

    // B fragments: 6 x b128 (L2-hot 6KB table), constant across gens.
    short8v Bf[6];
    #pragma unroll
    for (int m = 0; m < 6; ++m)
        Bf[m] = *reinterpret_cast<const short8v*>(Bpk + (m * 64 + lane) * 8);

    const int q = lane >> 4, r = lane & 15;
    const int col = r;                             // C/D col = lane&15
    const int D = col / 5, d = col - 5 * D;        // phase-set, phase
    const int aoff = 1152 * wv + 72 * r + 8 * q;   // lane's A base (elems)

    for (int s = 0; s < n; ++s) {
        const int kgen = KB * (gb + s);            // gen's base k
        const int gg = 24 * kgen - 48;             // tile start; 16B-aligned
        __syncthreads();                           // prior gen's reads done

        if (gg >= 0 && gg + TILE_E <= NIN) {       // interior fast path
            const float4* __restrict__ p = reinterpret_cast<const float4*>(xr + gg);
            auto stu = [&](int u) {                // 8 floats -> b128 write
                const float4 pa = p[2 * u], pb = p[2 * u + 1];
                unsigned r0, r1, r2, r3;
                asm("v_cvt_pk_bf16_f32 %0, %1, %2" : "=v"(r0) : "v"(pa.x), "v"(pa.y));
                asm("v_cvt_pk_bf16_f32 %0, %1, %2" : "=v"(r1) : "v"(pa.z), "v"(pa.w));
                asm("v_cvt_pk_bf16_f32 %0, %1, %2" : "=v"(r2) : "v"(pb.x), "v"(pb.y));
                asm("v_cvt_pk_bf16_f32 %0, %1, %2" : "=v"(r3) : "v"(pb.z), "v"(pb.w));
                *reinterpret_cast<uint4*>(&ldsb[8 * u]) = make_uint4(r0, r1, r2, r3);
            };
            stu(tid);
            stu(tid + 256);
            if (tid < NU8 - 512) stu(tid + 512);
        } else {                                   // first/last gens only
            auto stu = [&](int u) {
                float v[8];
                #pragma unroll
                for (int j = 0; j < 8; ++j) {
                    const int g = gg + 8 * u + j;
                    v[j] = ((unsigned)g < NIN) ? xr[g] : 0.0f;
                }
                unsigned r0, r1, r2, r3;
                asm("v_cvt_pk_bf16_f32 %0, %1, %2" : "=v"(r0) : "v"(v[0]), "v"(v[1]));
                asm("v_cvt_pk_bf16_f32 %0, %1, %2" : "=v"(r1) : "v"(v[2]), "v"(v[3]));
                asm("v_cvt_pk_bf16_f32 %0, %1, %2" : "=v"(r2) : "v"(v[4]), "v"(v[5]));
                asm("v_cvt_pk_bf16_f32 %0, %1, %2" : "=v"(r3) : "v"(v[6]), "v"(v[7]));
                *reinterpret_cast<uint4*>(&ldsb[8 * u]) = make_uint4(r0, r1, r2, r3);
            };
            stu(tid);
            stu(tid + 256);
            if (tid < NU8 - 512) stu(tid + 512);
        }
        __syncthreads();                           // tile staged

        // ---- compute: A fragments + MFMA chain over K=192 ----
        const short* __restrict__ ap = &ldsb[aoff];
        float4v acc = {0.f, 0.f, 0.f, 0.f};
        #pragma unroll
        for (int m = 0; m < 6; ++m) {
            const short8v A = *reinterpret_cast<const short8v*>(ap + 32 * m);
            acc = __builtin_amdgcn_mfma_f32_16x16x32_bf16(A, Bf[m], acc, 0, 0, 0);
        }

        // ---- stores: k = kgen + 48wv + 12q + 3*reg + D, phase d ----
        if (col < 15) {
            const int kw = kgen + 48 * wv + 12 * q + D;
            float* __restrict__ yr = y + (size_t)row * NOUTR;
            #pragma unroll
            for (int jj = 0; jj < 4; ++jj) {
                const int k = kw + 3 * jj;
                if (k < KTOT) yr[5 * (size_t)k + d] = acc[jj];
            }
        }
    }
}

extern "C" void kernel_launch(void* const* d_in, const int* in_sizes, int n_in,
                              void* d_out, int out_size, void* d_ws, size_t ws_size,
                              hipStream_t stream) {
    const float* x = (const float*)d_in[0];
    const float* h = (const float*)d_in[1];        // 481 taps
    float* y = (float*)d_out;                      // 32 x 300000 f32
    unsigned short* Bpk = (unsigned short*)d_ws;   // 6KB packed B fragments

    prep_taps_kernel<<<12, 256, 0, stream>>>(h, Bpk);
    dim3 grid(NBX, NROWS);                         // 79 x 32, 256-thr blocks
    resample_kernel<<<grid, 256, 0, stream>>>(x, Bpk, y);
}